// Round 1
// baseline (136.998 us; speedup 1.0000x reference)
//
#include <hip/hip_runtime.h>

#define NGAUSS 2048
#define NPIX   65536
#define WID    512.0f
#define HEI    512.0f
#define CH     256   // gaussians per LDS chunk

// Per-gaussian packed params (12 floats, 48B, 16B-aligned):
// [0]=A [1]=B [2]=C [3]=D [4]=E0 [5]=E1 [6]=r [7]=g [8]=b [9..11]=pad
// dx = A*X + B*Y + E0 ; dy = C*X + D*Y + E1 ; w = exp2(-(dx^2+dy^2))
// A..D pre-scaled by sqrt(log2(e)) so exp(-q) == exp2(-q_scaled).

__global__ __launch_bounds__(256) void prep_kernel(
    const float* __restrict__ rgb, const float* __restrict__ mu,
    const float* __restrict__ scale, const float* __restrict__ angle,
    float* __restrict__ P)
{
    int n = blockIdx.x * blockDim.x + threadIdx.x;
    if (n >= NGAUSS) return;
    const float MU_BORDER = 1.05f;
    const float S_MIN = 1.0f / 30.0f;
    const float S_MAX = 1.0f / 0.75f;
    const float PI_APPROX = 3.1416f;
    const float K = 1.2011224087864498f;  // sqrt(log2(e))

    float mx = tanhf(mu[2*n+0]) * MU_BORDER * (0.5f * WID);
    float my = tanhf(mu[2*n+1]) * MU_BORDER * (0.5f * HEI);
    float al = tanhf(angle[n]) * PI_APPROX;
    float c = cosf(al);
    float s = sinf(al);
    float S0 = 1.0f / (1.0f + expf(-scale[2*n+0])) * (S_MAX - S_MIN) + S_MIN;
    float S1 = 1.0f / (1.0f + expf(-scale[2*n+1])) * (S_MAX - S_MIN) + S_MIN;

    // d1x = S0*(c*vx - s*vy), d1y = S1*(s*vx + c*vy), vx = X - mx, vy = Y - my
    float A  =  S0 * c * K;
    float Bc = -(S0 * s * K);
    float C  =  S1 * s * K;
    float D  =  S1 * c * K;
    float E0 = -(A * mx + Bc * my);
    float E1 = -(C * mx + D  * my);

    float r = 1.0f / (1.0f + expf(-rgb[3*n+0]));
    float g = 1.0f / (1.0f + expf(-rgb[3*n+1]));
    float b = 1.0f / (1.0f + expf(-rgb[3*n+2]));

    float* p = P + 12 * n;
    p[0] = A;  p[1] = Bc; p[2] = C;  p[3] = D;
    p[4] = E0; p[5] = E1; p[6] = r;  p[7] = g;
    p[8] = b;  p[9] = 0.f; p[10] = 0.f; p[11] = 0.f;
}

__global__ __launch_bounds__(256) void splat_kernel(
    const float2* __restrict__ x, const float* __restrict__ P,
    float* __restrict__ out)
{
    // double-buffered staging: 2 x 256 gaussians x 48B = 24 KiB LDS
    __shared__ float4 sh[2][CH * 3];

    int t = blockIdx.x * 256 + threadIdx.x;
    float2 xy = x[t];
    float X = xy.x - 0.5f * WID;
    float Y = xy.y - 0.5f * HEI;

    const float4* P4 = (const float4*)P;

    // stage chunk 0
    for (int i = threadIdx.x; i < CH * 3; i += 256)
        sh[0][i] = P4[i];

    float ar = 0.f, ag = 0.f, ab = 0.f;
    const int NCHUNK = NGAUSS / CH;

    for (int ch = 0; ch < NCHUNK; ++ch) {
        __syncthreads();
        // prefetch next chunk into the other buffer while computing this one
        if (ch + 1 < NCHUNK) {
            const float4* src = P4 + (ch + 1) * CH * 3;
            float4* dst = &sh[(ch + 1) & 1][0];
            for (int i = threadIdx.x; i < CH * 3; i += 256)
                dst[i] = src[i];
        }
        const float4* g = &sh[ch & 1][0];
        #pragma unroll 4
        for (int j = 0; j < CH; ++j) {
            float4 c0 = g[3*j + 0];   // A, B, C, D
            float4 c1 = g[3*j + 1];   // E0, E1, r, g
            float4 c2 = g[3*j + 2];   // b, pad...
            float dx = fmaf(c0.x, X, fmaf(c0.y, Y, c1.x));
            float dy = fmaf(c0.z, X, fmaf(c0.w, Y, c1.y));
            float q  = fmaf(dx, dx, dy * dy);
            float w  = __builtin_amdgcn_exp2f(-q);   // neg folds as src modifier
            ar = fmaf(w, c1.z, ar);
            ag = fmaf(w, c1.w, ag);
            ab = fmaf(w, c2.x, ab);
        }
    }

    out[3*t + 0] = ar;
    out[3*t + 1] = ag;
    out[3*t + 2] = ab;
}

extern "C" void kernel_launch(void* const* d_in, const int* in_sizes, int n_in,
                              void* d_out, int out_size, void* d_ws, size_t ws_size,
                              hipStream_t stream) {
    const float* x     = (const float*)d_in[0];  // [B,2]
    const float* rgb   = (const float*)d_in[1];  // [N,3]
    const float* mu    = (const float*)d_in[2];  // [N,2]
    const float* scale = (const float*)d_in[3];  // [N,2]
    const float* angle = (const float*)d_in[4];  // [N]
    float* P = (float*)d_ws;                     // 2048*12*4 = 96 KiB

    hipLaunchKernelGGL(prep_kernel, dim3(NGAUSS / 256), dim3(256), 0, stream,
                       rgb, mu, scale, angle, P);
    hipLaunchKernelGGL(splat_kernel, dim3(NPIX / 256), dim3(256), 0, stream,
                       (const float2*)x, P, (float*)d_out);
}

// Round 2
// 101.907 us; speedup vs baseline: 1.3443x; 1.3443x over previous
//
#include <hip/hip_runtime.h>

#define NGAUSS 2048
#define NPIX   65536
#define WID    512.0f
#define HEI    512.0f
#define NSLICE 8                 // N-dimension split for occupancy
#define GPB    (NGAUSS / NSLICE) // 256 gaussians per block
#define PPB    256               // pixels per block

// Per-gaussian packed params in LDS (3 x float4 = 48 B):
// c0 = (A, B, C, D) ; c1 = (E0, E1, r, g) ; c2 = (b, 0, 0, 0)
// dx = A*X + B*Y + E0 ; dy = C*X + D*Y + E1 ; w = exp2(-(dx^2+dy^2))
// A..E pre-scaled by sqrt(log2(e)) so exp(-q) == exp2(-q_scaled).

__global__ __launch_bounds__(256) void splat_kernel(
    const float2* __restrict__ x, const float* __restrict__ rgb,
    const float* __restrict__ mu, const float* __restrict__ scale,
    const float* __restrict__ angle, float* __restrict__ out)
{
    __shared__ float4 sh[GPB * 3];   // 12 KiB

    const int slice = blockIdx.x & (NSLICE - 1);
    const int pg    = blockIdx.x >> 3;          // pixel group 0..255
    const int tid   = threadIdx.x;

    // ---- fused prep: thread tid preps gaussian (slice*GPB + tid) ----
    {
        const float MU_BORDER = 1.05f;
        const float S_MIN = 1.0f / 30.0f;
        const float S_MAX = 1.0f / 0.75f;
        const float PI_APPROX = 3.1416f;
        const float K = 1.2011224087864498f;  // sqrt(log2(e))

        int n = slice * GPB + tid;
        float mx = tanhf(mu[2*n+0]) * MU_BORDER * (0.5f * WID);
        float my = tanhf(mu[2*n+1]) * MU_BORDER * (0.5f * HEI);
        float al = tanhf(angle[n]) * PI_APPROX;
        float c = cosf(al);
        float s = sinf(al);
        float S0 = 1.0f / (1.0f + expf(-scale[2*n+0])) * (S_MAX - S_MIN) + S_MIN;
        float S1 = 1.0f / (1.0f + expf(-scale[2*n+1])) * (S_MAX - S_MIN) + S_MIN;

        float A  =  S0 * c * K;
        float Bc = -(S0 * s * K);
        float C  =  S1 * s * K;
        float D  =  S1 * c * K;
        float E0 = -(A * mx + Bc * my);
        float E1 = -(C * mx + D  * my);

        float r = 1.0f / (1.0f + expf(-rgb[3*n+0]));
        float g = 1.0f / (1.0f + expf(-rgb[3*n+1]));
        float b = 1.0f / (1.0f + expf(-rgb[3*n+2]));

        sh[3*tid + 0] = make_float4(A, Bc, C, D);
        sh[3*tid + 1] = make_float4(E0, E1, r, g);
        sh[3*tid + 2] = make_float4(b, 0.f, 0.f, 0.f);
    }
    __syncthreads();

    // ---- splat: one pixel per thread over this block's 256 gaussians ----
    const int t = pg * PPB + tid;
    float2 xy = x[t];
    float X = xy.x - 0.5f * WID;
    float Y = xy.y - 0.5f * HEI;

    float ar = 0.f, ag = 0.f, ab = 0.f;
    #pragma unroll 4
    for (int j = 0; j < GPB; ++j) {
        float4 c0 = sh[3*j + 0];
        float4 c1 = sh[3*j + 1];
        float4 c2 = sh[3*j + 2];
        float dx = fmaf(c0.x, X, fmaf(c0.y, Y, c1.x));
        float dy = fmaf(c0.z, X, fmaf(c0.w, Y, c1.y));
        float q  = fmaf(dx, dx, dy * dy);
        float w  = __builtin_amdgcn_exp2f(-q);
        ar = fmaf(w, c1.z, ar);
        ag = fmaf(w, c1.w, ag);
        ab = fmaf(w, c2.x, ab);
    }

    atomicAdd(&out[3*t + 0], ar);
    atomicAdd(&out[3*t + 1], ag);
    atomicAdd(&out[3*t + 2], ab);
}

extern "C" void kernel_launch(void* const* d_in, const int* in_sizes, int n_in,
                              void* d_out, int out_size, void* d_ws, size_t ws_size,
                              hipStream_t stream) {
    const float* x     = (const float*)d_in[0];  // [B,2]
    const float* rgb   = (const float*)d_in[1];  // [N,3]
    const float* mu    = (const float*)d_in[2];  // [N,2]
    const float* scale = (const float*)d_in[3];  // [N,2]
    const float* angle = (const float*)d_in[4];  // [N]

    // harness poisons d_out with 0xAA — zero it (async, graph-capture safe)
    hipMemsetAsync(d_out, 0, (size_t)out_size * sizeof(float), stream);

    hipLaunchKernelGGL(splat_kernel, dim3(NPIX / PPB * NSLICE), dim3(256), 0, stream,
                       (const float2*)x, rgb, mu, scale, angle, (float*)d_out);
}